// Round 1
// baseline (2468.316 us; speedup 1.0000x reference)
//
#include <hip/hip_runtime.h>

// Problem constants (from reference): B=8, C=32, H=256, W=448, kernel_size=1
constexpr int B = 8;
constexpr int C = 32;
constexpr int H = 256;
constexpr int W = 448;
constexpr int HW = H * W;

__global__ void splat_kernel(const float* __restrict__ in1,
                             const float* __restrict__ flow,
                             float* __restrict__ out) {
    int idx = blockIdx.x * blockDim.x + threadIdx.x;  // over B*H*W pixels
    if (idx >= B * HW) return;
    int b = idx / HW;
    int p = idx - b * HW;
    int y = p / W;
    int x = p - y * W;

    float u = flow[(b * 2 + 0) * HW + p];
    float v = flow[(b * 2 + 1) * HW + p];

    float tx = (float)x + u;
    float ty = (float)y + v;
    float fx0 = floorf(tx);
    float fy0 = floorf(ty);
    int x0 = (int)fx0;
    int y0 = (int)fy0;
    float fx = tx - fx0;
    float fy = ty - fy0;

    float w00 = (1.0f - fx) * (1.0f - fy);
    float w10 = fx * (1.0f - fy);
    float w01 = (1.0f - fx) * fy;
    float w11 = fx * fy;

    bool vx0 = (x0 >= 0) && (x0 < W);
    bool vx1 = (x0 + 1 >= 0) && (x0 + 1 < W);
    bool vy0 = (y0 >= 0) && (y0 < H);
    bool vy1 = (y0 + 1 >= 0) && (y0 + 1 < H);

    // Base offsets for the four corners (only used when valid)
    long o00 = (long)y0 * W + x0;
    long o10 = o00 + 1;
    long o01 = o00 + W;
    long o11 = o00 + W + 1;

    const float* src = in1 + (long)b * C * HW + p;
    float* dstb = out + (long)b * C * HW;

    for (int c = 0; c < C; ++c) {
        float val = src[(long)c * HW];
        float* ob = dstb + (long)c * HW;
        if (vx0 && vy0) atomicAdd(ob + o00, w00 * val);
        if (vx1 && vy0) atomicAdd(ob + o10, w10 * val);
        if (vx0 && vy1) atomicAdd(ob + o01, w01 * val);
        if (vx1 && vy1) atomicAdd(ob + o11, w11 * val);
    }
}

extern "C" void kernel_launch(void* const* d_in, const int* in_sizes, int n_in,
                              void* d_out, int out_size, void* d_ws, size_t ws_size,
                              hipStream_t stream) {
    const float* in1 = (const float*)d_in[0];
    const float* flow = (const float*)d_in[1];
    float* out = (float*)d_out;

    // Output is accumulated into — must be zeroed every call.
    hipMemsetAsync(out, 0, (size_t)out_size * sizeof(float), stream);

    int npix = B * HW;
    int block = 256;
    int grid = (npix + block - 1) / block;
    splat_kernel<<<grid, block, 0, stream>>>(in1, flow, out);
}

// Round 2
// 730.961 us; speedup vs baseline: 3.3768x; 3.3768x over previous
//
#include <hip/hip_runtime.h>

// Problem constants: B=8, C=32, H=256, W=448, kernel_size=1
constexpr int B = 8;
constexpr int C = 32;
constexpr int H = 256;
constexpr int W = 448;
constexpr int HW = H * W;

// Tiling: each block owns a TW x TH source tile of one batch image.
constexpr int TW = 64;           // tile width  (448/64 = 7)
constexpr int TH = 16;           // tile height (256/16 = 16)
constexpr int A  = 4;            // apron: covers |flow| <= 4 (N(0,1) => ~all)
constexpr int LW = TW + 2 * A;   // 72
constexpr int LH = TH + 2 * A;   // 24
constexpr int LSZ = LW * LH;     // 1728 floats = 6.9 KB
constexpr int NTHREADS = 256;
constexpr int PPT = (TW * TH) / NTHREADS;  // 4 pixels per thread

__global__ __launch_bounds__(NTHREADS)
void splat_tiled(const float* __restrict__ in1,
                 const float* __restrict__ flow,
                 float* __restrict__ out) {
    __shared__ float acc[LSZ];

    int bid = blockIdx.x;
    // XCD-aware decomposition: batch = bid % 8 -> each batch image's output
    // is only touched by blocks on one XCD (round-robin dispatch heuristic;
    // correctness does not depend on it).
    int b = bid & 7;
    int t = bid >> 3;          // 0..111 : 16 ty x 7 tx
    int ty = t / 7;
    int tx = t - ty * 7;
    int ox = tx * TW;
    int oy = ty * TH;
    int tid = threadIdx.x;

    // ---- Precompute per-pixel splat geometry once (reused for all 32 ch) ----
    int   lidx[PPT];   // LDS index of corner (0,0), or -1 -> outlier path
    int   pxy[PPT];    // packed (x0+16) | (y0+16)<<16 for outlier path
    float w00[PPT], w10[PPT], w01[PPT], w11[PPT];
#pragma unroll
    for (int k = 0; k < PPT; ++k) {
        int p  = tid + k * NTHREADS;      // 0..1023 within tile
        int py = p >> 6;                  // TW = 64
        int px = p & 63;
        int gx = ox + px;
        int gy = oy + py;
        int fo = b * 2 * HW + gy * W + gx;
        float u = flow[fo];
        float v = flow[fo + HW];
        float txf = (float)gx + u;
        float tyf = (float)gy + v;
        float fx0 = floorf(txf);
        float fy0 = floorf(tyf);
        int x0 = (int)fx0;
        int y0 = (int)fy0;
        float fx = txf - fx0;
        float fy = tyf - fy0;
        w00[k] = (1.0f - fx) * (1.0f - fy);
        w10[k] = fx * (1.0f - fy);
        w01[k] = (1.0f - fx) * fy;
        w11[k] = fx * fy;
        // clamp far outliers into a safe packing range (they fail all
        // validity tests either way -> semantics unchanged)
        x0 = min(max(x0, -8), W + 8);
        y0 = min(max(y0, -8), H + 8);
        int lx = x0 - (ox - A);
        int ly = y0 - (oy - A);
        bool in_lds = (lx >= 0) && (lx + 1 < LW) && (ly >= 0) && (ly + 1 < LH);
        lidx[k] = in_lds ? (ly * LW + lx) : -1;
        pxy[k]  = (x0 + 16) | ((y0 + 16) << 16);
    }

    // zero LDS accumulator
    for (int i = tid; i < LSZ; i += NTHREADS) acc[i] = 0.0f;
    __syncthreads();

    const float* inb  = in1 + (size_t)b * C * HW;
    float*       outb = out + (size_t)b * C * HW;

    for (int c = 0; c < C; ++c) {
        const float* inp  = inb  + (size_t)c * HW;
        float*       outp = outb + (size_t)c * HW;

        // splat this channel into LDS
#pragma unroll
        for (int k = 0; k < PPT; ++k) {
            int p  = tid + k * NTHREADS;
            int py = p >> 6;
            int px = p & 63;
            float val = inp[(oy + py) * W + (ox + px)];   // coalesced
            int li = lidx[k];
            if (li >= 0) {
                atomicAdd(&acc[li],          w00[k] * val);
                atomicAdd(&acc[li + 1],      w10[k] * val);
                atomicAdd(&acc[li + LW],     w01[k] * val);
                atomicAdd(&acc[li + LW + 1], w11[k] * val);
            } else {
                // rare outlier: direct global atomics with per-corner checks
                int x0 = (pxy[k] & 0xffff) - 16;
                int y0 = (pxy[k] >> 16) - 16;
                bool vx0 = (x0 >= 0) && (x0 < W);
                bool vx1 = (x0 + 1 >= 0) && (x0 + 1 < W);
                bool vy0 = (y0 >= 0) && (y0 < H);
                bool vy1 = (y0 + 1 >= 0) && (y0 + 1 < H);
                long o00 = (long)y0 * W + x0;
                if (vx0 && vy0) atomicAdd(outp + o00,         w00[k] * val);
                if (vx1 && vy0) atomicAdd(outp + o00 + 1,     w10[k] * val);
                if (vx0 && vy1) atomicAdd(outp + o00 + W,     w01[k] * val);
                if (vx1 && vy1) atomicAdd(outp + o00 + W + 1, w11[k] * val);
            }
        }
        __syncthreads();

        // flush LDS tile to global (and re-zero for next channel)
        for (int i = tid; i < LSZ; i += NTHREADS) {
            float v = acc[i];
            acc[i] = 0.0f;
            if (v != 0.0f) {
                int ly = i / LW;
                int lx = i - ly * LW;
                int gy = oy - A + ly;
                int gx = ox - A + lx;
                if (gx >= 0 && gx < W && gy >= 0 && gy < H)
                    atomicAdd(outp + gy * W + gx, v);   // coalesced in x
            }
        }
        __syncthreads();
    }
}

extern "C" void kernel_launch(void* const* d_in, const int* in_sizes, int n_in,
                              void* d_out, int out_size, void* d_ws, size_t ws_size,
                              hipStream_t stream) {
    const float* in1  = (const float*)d_in[0];
    const float* flow = (const float*)d_in[1];
    float* out = (float*)d_out;

    // Output is accumulated into -> must be zeroed every call.
    hipMemsetAsync(out, 0, (size_t)out_size * sizeof(float), stream);

    int nblocks = B * (H / TH) * (W / TW);   // 8 * 16 * 7 = 896
    splat_tiled<<<nblocks, NTHREADS, 0, stream>>>(in1, flow, out);
}